// Round 6
// baseline (408.492 us; speedup 1.0000x reference)
//
#include <hip/hip_runtime.h>
#include <stdint.h>
#include <math.h>

// MixtureOfDepths: B=4, L=4096, D=1024, Dff=4096, capacity 0.5 -> k=2048.
// Inputs/output FP32; compute bf16 MFMA (fp32 accumulate).
// R5 -> R6: (1) LDS 33280->32768 (rs[] -> direct global rows reads) for
// 5 blocks/CU; (2) 16x16x32 -> 32x32x16 MFMA (fewer matrix-pipe cycles);
// (3) router_cvt + cvt3 merged into one prep kernel.

typedef __attribute__((ext_vector_type(8))) __bf16 bf16x8;
typedef __attribute__((ext_vector_type(16))) float f32x16;

__device__ __forceinline__ void async_cp16(const __bf16* g, __bf16* l) {
    __builtin_amdgcn_global_load_lds(
        (__attribute__((address_space(1))) void*)g,
        (__attribute__((address_space(3))) void*)l,
        16, 0, 0);
}

// gelu_tanh(x) == x * sigmoid(2*0.7978845608*(x + 0.044715 x^3)), exactly.
__device__ __forceinline__ float gelu_fast(float x) {
    float u = 1.5957691216057308f * x * (1.0f + 0.044715f * x * x);
    return x / (1.0f + __expf(-u));
}

// ---------- fused prep: router scores + x->bf16  |  weights->bf16 ----------
// Blocks [0,4096): one wave per token, score + convert (score math must stay
// bit-identical across rounds: selection boundary).
// Blocks [4096,8704): 8-elem chunks over wb|w1|w2.
__global__ __launch_bounds__(256) void prep(
    const float* __restrict__ x, const float* __restrict__ wr,
    float* __restrict__ scores, __bf16* __restrict__ xb,
    const float* __restrict__ wb, const float* __restrict__ w1,
    const float* __restrict__ w2,
    __bf16* __restrict__ wbb, __bf16* __restrict__ w1b, __bf16* __restrict__ w2b)
{
    const int bid = blockIdx.x;
    if (bid < 4096) {
        int wid  = (bid * 256 + threadIdx.x) >> 6;  // token id
        int lane = threadIdx.x & 63;
        const float* row = x + (size_t)wid * 1024;
        __bf16* orow = xb + (size_t)wid * 1024;
        double s = 0.0;
        #pragma unroll
        for (int it = 0; it < 2; ++it) {
            int base = it * 512 + lane * 8;
            float4 a  = *(const float4*)(row + base);
            float4 b  = *(const float4*)(row + base + 4);
            float4 wa = *(const float4*)(wr + base);
            float4 wc = *(const float4*)(wr + base + 4);
            s += (double)a.x * wa.x + (double)a.y * wa.y
               + (double)a.z * wa.z + (double)a.w * wa.w
               + (double)b.x * wc.x + (double)b.y * wc.y
               + (double)b.z * wc.z + (double)b.w * wc.w;
            bf16x8 v;
            v[0] = (__bf16)a.x; v[1] = (__bf16)a.y; v[2] = (__bf16)a.z; v[3] = (__bf16)a.w;
            v[4] = (__bf16)b.x; v[5] = (__bf16)b.y; v[6] = (__bf16)b.z; v[7] = (__bf16)b.w;
            *(bf16x8*)(orow + base) = v;
        }
        #pragma unroll
        for (int off = 32; off > 0; off >>= 1) s += __shfl_down(s, off, 64);
        if (lane == 0) scores[wid] = (float)s;
    } else {
        const int c0 = 131072, c1 = 524288;  // wb, w1 chunk counts (w2 = c1)
        int chunk = (bid - 4096) * 256 + threadIdx.x;
        const float* in; __bf16* out;
        if (chunk < c0)           { in = wb + (size_t)chunk * 8;              out = wbb + (size_t)chunk * 8; }
        else if (chunk < c0 + c1) { int c = chunk - c0;      in = w1 + (size_t)c * 8; out = w1b + (size_t)c * 8; }
        else                      { int c = chunk - c0 - c1; in = w2 + (size_t)c * 8; out = w2b + (size_t)c * 8; }
        float4 a = *(const float4*)(in);
        float4 b = *(const float4*)(in + 4);
        bf16x8 v;
        v[0] = (__bf16)a.x; v[1] = (__bf16)a.y; v[2] = (__bf16)a.z; v[3] = (__bf16)a.w;
        v[4] = (__bf16)b.x; v[5] = (__bf16)b.y; v[6] = (__bf16)b.z; v[7] = (__bf16)b.w;
        *(bf16x8*)(out) = v;
    }
}

// ---------------- per-batch top-k via 8-bit MSB-first radix select ----------------
__global__ __launch_bounds__(1024) void topk_build(
    const float* __restrict__ scores,
    int* __restrict__ sel_rows, int* __restrict__ byp_rows)
{
    const int L = 4096, K = 2048;
    __shared__ unsigned u[4096];
    __shared__ int hist[256];
    __shared__ int scan_s[1024];
    __shared__ unsigned s_pref;
    __shared__ int s_kk;
    int b = blockIdx.x, t = threadIdx.x;

    for (int i = t; i < L; i += 1024) {
        unsigned v = __float_as_uint(scores[b * L + i]);
        v = (v & 0x80000000u) ? ~v : (v | 0x80000000u);
        u[i] = v;
    }
    if (t == 0) { s_pref = 0; s_kk = K; }
    __syncthreads();

    for (int shift = 24; shift >= 0; shift -= 8) {
        if (t < 256) hist[t] = 0;
        __syncthreads();
        unsigned pref = s_pref;
        for (int i = t; i < L; i += 1024) {
            unsigned v = u[i];
            bool in_set = (shift == 24) || ((v >> (shift + 8)) == pref);
            if (in_set) atomicAdd(&hist[(v >> shift) & 255], 1);
        }
        __syncthreads();
        if (t == 0) {
            int kk = s_kk, cum = 0, bsel = 0;
            for (int j = 255; j >= 0; --j) {
                if (cum + hist[j] >= kk) { bsel = j; break; }
                cum += hist[j];
            }
            s_kk = kk - cum;
            s_pref = (pref << 8) | (unsigned)bsel;
        }
        __syncthreads();
    }
    unsigned thr = s_pref;
    int need = s_kk;

    int base = t * 4;
    unsigned v0 = u[base], v1 = u[base+1], v2 = u[base+2], v3 = u[base+3];
    int eq0 = (v0 == thr), eq1 = (v1 == thr), eq2 = (v2 == thr), eq3 = (v3 == thr);
    scan_s[t] = eq0 + eq1 + eq2 + eq3;
    __syncthreads();
    for (int off = 1; off < 1024; off <<= 1) {
        int v = scan_s[t];
        if (t >= off) v += scan_s[t - off];
        __syncthreads();
        scan_s[t] = v;
        __syncthreads();
    }
    int erun = (t > 0) ? scan_s[t - 1] : 0;
    int sel[4];
    {
        int r = erun;
        sel[0] = (v0 > thr) || (eq0 && r < need); r += eq0;
        sel[1] = (v1 > thr) || (eq1 && r < need); r += eq1;
        sel[2] = (v2 > thr) || (eq2 && r < need); r += eq2;
        sel[3] = (v3 > thr) || (eq3 && r < need);
    }
    __syncthreads();

    scan_s[t] = sel[0] + sel[1] + sel[2] + sel[3];
    __syncthreads();
    for (int off = 1; off < 1024; off <<= 1) {
        int v = scan_s[t];
        if (t >= off) v += scan_s[t - off];
        __syncthreads();
        scan_s[t] = v;
        __syncthreads();
    }
    int run = (t > 0) ? scan_s[t - 1] : 0;
    #pragma unroll
    for (int j = 0; j < 4; ++j) {
        int idx = base + j;
        if (sel[j]) { sel_rows[b * K + run] = b * L + idx; run++; }
        else        { byp_rows[b * (L - K) + (idx - run)] = b * L + idx; }
    }
}

// XCD swizzle: with round-robin block->XCD (id%8), put all n-tiles of one
// m-tile on one XCD so the A-tile's reuse hits that XCD's L2.
__device__ __forceinline__ void xcd_map(int id, int nx, int& mt, int& nt) {
    int grp = nx * 8;
    mt = (id / grp) * 8 + (id & 7);
    nt = (id % grp) >> 3;
}

// ======== async GEMM, 32x32x16 MFMA, all-bf16 operands ========
// C[m,n] = sum_k A[m,k]*W[n,k]; 128x128 tile, BK=64, 4 waves (2x2 of 64x64),
// each wave 2x2 frags of 32x32. LDS exactly 32KB -> 5 blocks/CU.
// XOR-swizzled LDS: slot s of row r holds chunk s^(r&7) (8 bf16 chunks).
template <bool GATHER_A, bool SCATTER_OUT, bool GELU_ACT, typename OT>
__global__ __launch_bounds__(256, 5) void gemm32(
    const __bf16* __restrict__ A, const __bf16* __restrict__ W,
    OT* __restrict__ Out, const int* __restrict__ rows,
    int K, int lda, int ldo)
{
    constexpr int BM = 128, BK = 64;
    __shared__ __align__(16) __bf16 As[BM * BK];
    __shared__ __align__(16) __bf16 Bs[BM * BK];

    const int tid = threadIdx.x;
    int mt, nt;
    xcd_map(blockIdx.y * gridDim.x + blockIdx.x, gridDim.x, mt, nt);
    const int m0 = mt * BM, n0 = nt * BM;

    const int sub = tid >> 3;
    const int gc  = (tid & 7) ^ (sub & 7);
    const __bf16* aptr[4]; const __bf16* bptr[4];
    __bf16* adst[4]; __bf16* bdst[4];
    #pragma unroll
    for (int i = 0; i < 4; ++i) {
        int row = i * 32 + sub;
        int ar  = GATHER_A ? rows[m0 + row] : (m0 + row);
        aptr[i] = A + (size_t)ar * lda + gc * 8;
        bptr[i] = W + (size_t)(n0 + row) * K + gc * 8;
        adst[i] = As + (i * 256 + tid) * 8;
        bdst[i] = Bs + (i * 256 + tid) * 8;
    }

    f32x16 acc[2][2] = {};
    const int lane = tid & 63;
    const int wv = tid >> 6;
    const int wr = (wv >> 1) * 64, wc = (wv & 1) * 64;
    const int col = lane & 31, half = lane >> 5;

    for (int k0 = 0; k0 < K; k0 += BK) {
        #pragma unroll
        for (int i = 0; i < 4; ++i) async_cp16(aptr[i] + k0, adst[i]);
        #pragma unroll
        for (int i = 0; i < 4; ++i) async_cp16(bptr[i] + k0, bdst[i]);
        __syncthreads();

        #pragma unroll
        for (int ks = 0; ks < 4; ++ks) {       // K-chunks of 16
            int c = ks * 2 + half;             // 8-bf16 chunk index
            bf16x8 af[2], bfm[2];
            #pragma unroll
            for (int mi = 0; mi < 2; ++mi) {
                int row = wr + mi * 32 + col;
                af[mi] = *(const bf16x8*)(As + row * BK + (c ^ (row & 7)) * 8);
            }
            #pragma unroll
            for (int ni = 0; ni < 2; ++ni) {
                int row = wc + ni * 32 + col;
                bfm[ni] = *(const bf16x8*)(Bs + row * BK + (c ^ (row & 7)) * 8);
            }
            #pragma unroll
            for (int mi = 0; mi < 2; ++mi)
                #pragma unroll
                for (int ni = 0; ni < 2; ++ni)
                    acc[mi][ni] = __builtin_amdgcn_mfma_f32_32x32x16_bf16(
                        af[mi], bfm[ni], acc[mi][ni], 0, 0, 0);
        }
        __syncthreads();
    }

    // C/D layout [m74/m101]: col=lane&31, row=(reg&3)+8*(reg>>2)+4*(lane>>5)
    #pragma unroll
    for (int mi = 0; mi < 2; ++mi) {
        #pragma unroll
        for (int reg = 0; reg < 16; ++reg) {
            int rowl = wr + mi * 32 + (reg & 3) + 8 * (reg >> 2) + 4 * half;
            int orow = SCATTER_OUT ? rows[m0 + rowl] : (m0 + rowl);
            OT* op = Out + (size_t)orow * ldo + n0;
            #pragma unroll
            for (int ni = 0; ni < 2; ++ni) {
                float v = acc[mi][ni][reg];
                if (GELU_ACT) v = gelu_fast(v);
                op[wc + ni * 32 + col] = (OT)v;
            }
        }
    }
}

// ======== merged tail (32x32 frags): z==0 FFN2 (h@w2^T, scatter sel),
//                                     z==1 bypass (x@wb^T, gather+scatter byp) ====
__global__ __launch_bounds__(256, 5) void gemm_tail32(
    const __bf16* __restrict__ h, const __bf16* __restrict__ w2b,
    const __bf16* __restrict__ xb, const __bf16* __restrict__ wbb,
    float* __restrict__ Out,
    const int* __restrict__ sel_rows, const int* __restrict__ byp_rows)
{
    constexpr int BM = 128, BK = 64;
    __shared__ __align__(16) __bf16 As[BM * BK];
    __shared__ __align__(16) __bf16 Bs[BM * BK];

    const int z = blockIdx.z;
    const __bf16* A = z ? xb : h;
    const __bf16* W = z ? wbb : w2b;
    const int K = z ? 1024 : 4096;            // == lda for both
    const int* rows = z ? byp_rows : sel_rows;
    const bool gat = (z != 0);

    const int tid = threadIdx.x;
    int mt, nt;
    xcd_map(blockIdx.y * gridDim.x + blockIdx.x, gridDim.x, mt, nt);
    const int m0 = mt * BM, n0 = nt * BM;

    const int sub = tid >> 3;
    const int gc  = (tid & 7) ^ (sub & 7);
    const __bf16* aptr[4]; const __bf16* bptr[4];
    __bf16* adst[4]; __bf16* bdst[4];
    #pragma unroll
    for (int i = 0; i < 4; ++i) {
        int row = i * 32 + sub;
        int ar  = gat ? rows[m0 + row] : (m0 + row);
        aptr[i] = A + (size_t)ar * K + gc * 8;
        bptr[i] = W + (size_t)(n0 + row) * K + gc * 8;
        adst[i] = As + (i * 256 + tid) * 8;
        bdst[i] = Bs + (i * 256 + tid) * 8;
    }

    f32x16 acc[2][2] = {};
    const int lane = tid & 63;
    const int wv = tid >> 6;
    const int wrr = (wv >> 1) * 64, wc = (wv & 1) * 64;
    const int col = lane & 31, half = lane >> 5;

    for (int k0 = 0; k0 < K; k0 += BK) {
        #pragma unroll
        for (int i = 0; i < 4; ++i) async_cp16(aptr[i] + k0, adst[i]);
        #pragma unroll
        for (int i = 0; i < 4; ++i) async_cp16(bptr[i] + k0, bdst[i]);
        __syncthreads();

        #pragma unroll
        for (int ks = 0; ks < 4; ++ks) {
            int c = ks * 2 + half;
            bf16x8 af[2], bfm[2];
            #pragma unroll
            for (int mi = 0; mi < 2; ++mi) {
                int row = wrr + mi * 32 + col;
                af[mi] = *(const bf16x8*)(As + row * BK + (c ^ (row & 7)) * 8);
            }
            #pragma unroll
            for (int ni = 0; ni < 2; ++ni) {
                int row = wc + ni * 32 + col;
                bfm[ni] = *(const bf16x8*)(Bs + row * BK + (c ^ (row & 7)) * 8);
            }
            #pragma unroll
            for (int mi = 0; mi < 2; ++mi)
                #pragma unroll
                for (int ni = 0; ni < 2; ++ni)
                    acc[mi][ni] = __builtin_amdgcn_mfma_f32_32x32x16_bf16(
                        af[mi], bfm[ni], acc[mi][ni], 0, 0, 0);
        }
        __syncthreads();
    }

    #pragma unroll
    for (int mi = 0; mi < 2; ++mi) {
        #pragma unroll
        for (int reg = 0; reg < 16; ++reg) {
            int rowl = wrr + mi * 32 + (reg & 3) + 8 * (reg >> 2) + 4 * half;
            int orow = rows[m0 + rowl];
            float* op = Out + (size_t)orow * 1024 + n0;
            #pragma unroll
            for (int ni = 0; ni < 2; ++ni)
                op[wc + ni * 32 + col] = acc[mi][ni][reg];
        }
    }
}

extern "C" void kernel_launch(void* const* d_in, const int* in_sizes, int n_in,
                              void* d_out, int out_size, void* d_ws, size_t ws_size,
                              hipStream_t stream) {
    (void)in_sizes; (void)n_in; (void)out_size; (void)ws_size;
    const float* x  = (const float*)d_in[0];
    const float* wr = (const float*)d_in[1];
    const float* wb = (const float*)d_in[2];
    const float* w1 = (const float*)d_in[3];
    const float* w2 = (const float*)d_in[4];
    float* out = (float*)d_out;

    const int B = 4, L = 4096, D = 1024, DFF = 4096, KSEL = 2048;
    const int M = B * KSEL;           // 8192
    const int NTOK = B * L;           // 16384

    size_t n_x = (size_t)NTOK * D, n_wb = (size_t)D * D;
    size_t n_w1 = (size_t)DFF * D, n_w2 = (size_t)D * DFF;

    char* ws = (char*)d_ws;
    float* scores = (float*)ws;            ws += sizeof(float) * (size_t)NTOK;
    int* sel_rows = (int*)ws;              ws += sizeof(int) * (size_t)M;
    int* byp_rows = (int*)ws;              ws += sizeof(int) * (size_t)M;
    uintptr_t up = ((uintptr_t)ws + 255) & ~(uintptr_t)255;
    __bf16* xb  = (__bf16*)up;             up += 2 * n_x;
    __bf16* wbb = (__bf16*)up;             up += 2 * n_wb;
    __bf16* w1b = (__bf16*)up;             up += 2 * n_w1;
    __bf16* w2b = (__bf16*)up;             up += 2 * n_w2;
    up = (up + 255) & ~(uintptr_t)255;
    __bf16* h   = (__bf16*)up;             // 8192 x 4096 bf16 = 64 MiB

    // prep: blocks [0,4096) router+x-cvt, [4096,8704) weight cvt
    prep<<<8704, 256, 0, stream>>>(x, wr, scores, xb, wb, w1, w2, wbb, w1b, w2b);
    topk_build<<<B, 1024, 0, stream>>>(scores, sel_rows, byp_rows);

    // h = gelu(x[sel] @ w1^T)     (M=8192, N=DFF, K=D), 2048 blocks
    gemm32<true, false, true, __bf16>
        <<<dim3(DFF / 128, M / 128), 256, 0, stream>>>(
        xb, w1b, h, sel_rows, D, D, DFF);
    // merged: out[sel] = h @ w2^T  and  out[byp] = x[byp] @ wb^T, 1024 blocks
    gemm_tail32<<<dim3(D / 128, M / 128, 2), 256, 0, stream>>>(
        h, w2b, xb, wbb, out, sel_rows, byp_rows);
}